// Round 3
// baseline (917.067 us; speedup 1.0000x reference)
//
#include <hip/hip_runtime.h>
#include <math.h>

#define BB 4
#define NN 8192
#define PP 32768
#define KNN 16

// ---------------- embed1: h1 = pts @ w1 + b1  [P,64], fused BN stats ----------------
__global__ __launch_bounds__(256) void k_embed1(const float* __restrict__ pts,
    const float* __restrict__ w1, const float* __restrict__ b1, float* __restrict__ h1,
    float* __restrict__ gsum, float* __restrict__ gss)
{
  int tid = threadIdx.x;
  int c = tid & 63, g = tid >> 6;
  float wx = w1[c], wy = w1[64 + c], wz = w1[128 + c], bc = b1[c];
  int base = blockIdx.x * 256;
  float s = 0.f, ss = 0.f;
  #pragma unroll 4
  for (int i = 0; i < 64; ++i) {
    int p = base + g + i * 4;
    float px = pts[p*3+0], py = pts[p*3+1], pz = pts[p*3+2];
    float h = fmaf(pz, wz, fmaf(py, wy, fmaf(px, wx, bc)));
    h1[(size_t)p*64 + c] = h;
    s += h; ss = fmaf(h, h, ss);
  }
  __shared__ float ls[256], lq[256];
  ls[tid] = s; lq[tid] = ss;
  __syncthreads();
  if (tid < 64) {
    float a = ls[tid] + ls[tid+64] + ls[tid+128] + ls[tid+192];
    float b2 = lq[tid] + lq[tid+64] + lq[tid+128] + lq[tid+192];
    atomicAdd(gsum + tid, a);
    atomicAdd(gss + tid, b2);
  }
}

// ---------------- prep for kNN: pts4[p] = (x,y,z,|p|^2) ----------------
__global__ __launch_bounds__(256) void k_prep(const float* __restrict__ pts, float4* __restrict__ pts4)
{
  int p = blockIdx.x * 256 + threadIdx.x;
  float x = pts[p*3+0], y = pts[p*3+1], z = pts[p*3+2];
  float sq = __fadd_rn(__fadd_rn(__fmul_rn(x,x), __fmul_rn(y,y)), __fmul_rn(z,z));
  pts4[p] = make_float4(x, y, z, sq);
}

// ---------------- generic projection: out = relu(bn(in)) @ W (+bias), BN finalize inline,
// optional fused output stats. blockIdx.y selects one of up to 3 (W,bias,out) triples. ----------------
template<int K, int COUT>
__global__ __launch_bounds__(256) void k_proj(const float* __restrict__ in,
    const float* __restrict__ gsi, const float* __restrict__ gqi,
    const float* __restrict__ bng, const float* __restrict__ bnb,
    const float* __restrict__ W0, const float* __restrict__ W1, const float* __restrict__ W2,
    const float* __restrict__ B0, const float* __restrict__ B1, const float* __restrict__ B2,
    float* __restrict__ O0, float* __restrict__ O1, float* __restrict__ O2,
    float* __restrict__ gso, float* __restrict__ gqo)
{
  constexpr int PTS = 64;
  constexpr int CW = 8;
  constexpr int CG = COUT / CW;        // channel groups: 8 (COUT=64) or 16 (COUT=128)
  constexpr int PW = PTS * CG / 256;   // points per thread: 2 or 4
  const float* W  = (blockIdx.y == 0) ? W0 : (blockIdx.y == 1) ? W1 : W2;
  const float* Bb = (blockIdx.y == 0) ? B0 : (blockIdx.y == 1) ? B1 : B2;
  float*       O  = (blockIdx.y == 0) ? O0 : (blockIdx.y == 1) ? O1 : O2;
  __shared__ float xs[PTS][K + 1];
  __shared__ float scf[K], shf[K];
  int tid = threadIdx.x;
  int pbase = blockIdx.x * PTS;
  if (tid < K) {                       // inline BN finalize from raw sums
    float mean = gsi[tid] * (1.0f / PP);
    float var  = gqi[tid] * (1.0f / PP) - mean * mean;
    float sres = bng[tid] / sqrtf(var + 1e-5f);
    scf[tid] = sres;
    shf[tid] = bnb[tid] - mean * sres;
  }
  __syncthreads();
  constexpr int T4 = PTS * K / 4;
  for (int i = tid; i < T4; i += 256) {
    int p = i / (K/4), k = (i % (K/4)) * 4;
    float4 v = *(const float4*)(in + (size_t)(pbase + p)*K + k);
    v.x = fmaxf(fmaf(v.x, scf[k+0], shf[k+0]), 0.f);
    v.y = fmaxf(fmaf(v.y, scf[k+1], shf[k+1]), 0.f);
    v.z = fmaxf(fmaf(v.z, scf[k+2], shf[k+2]), 0.f);
    v.w = fmaxf(fmaf(v.w, scf[k+3], shf[k+3]), 0.f);
    xs[p][k+0] = v.x; xs[p][k+1] = v.y; xs[p][k+2] = v.z; xs[p][k+3] = v.w;
  }
  __syncthreads();
  int cg = tid % CG, pg = tid / CG;
  int c0 = cg * CW, p0 = pg * PW;
  float acc[PW][CW];
  #pragma unroll
  for (int i = 0; i < PW; ++i) {
    #pragma unroll
    for (int j = 0; j < CW; ++j) acc[i][j] = 0.f;
  }
  #pragma unroll 4
  for (int k = 0; k < K; ++k) {
    float4 wa = *(const float4*)(W + (size_t)k*COUT + c0);
    float4 wb = *(const float4*)(W + (size_t)k*COUT + c0 + 4);
    #pragma unroll
    for (int i = 0; i < PW; ++i) {
      float x = xs[p0 + i][k];
      acc[i][0] = fmaf(x, wa.x, acc[i][0]);
      acc[i][1] = fmaf(x, wa.y, acc[i][1]);
      acc[i][2] = fmaf(x, wa.z, acc[i][2]);
      acc[i][3] = fmaf(x, wa.w, acc[i][3]);
      acc[i][4] = fmaf(x, wb.x, acc[i][4]);
      acc[i][5] = fmaf(x, wb.y, acc[i][5]);
      acc[i][6] = fmaf(x, wb.z, acc[i][6]);
      acc[i][7] = fmaf(x, wb.w, acc[i][7]);
    }
  }
  float bj[CW];
  #pragma unroll
  for (int j = 0; j < CW; ++j) bj[j] = Bb ? Bb[c0 + j] : 0.f;
  float sts[CW], stq[CW];
  #pragma unroll
  for (int j = 0; j < CW; ++j) { sts[j] = 0.f; stq[j] = 0.f; }
  #pragma unroll
  for (int i = 0; i < PW; ++i) {
    float o[CW];
    #pragma unroll
    for (int j = 0; j < CW; ++j) {
      o[j] = acc[i][j] + bj[j];
      sts[j] += o[j];
      stq[j] = fmaf(o[j], o[j], stq[j]);
    }
    float* op = O + (size_t)(pbase + p0 + i)*COUT + c0;
    *(float4*)(op)     = make_float4(o[0], o[1], o[2], o[3]);
    *(float4*)(op + 4) = make_float4(o[4], o[5], o[6], o[7]);
  }
  if (gso) {                           // fused output stats (single-output dispatches only)
    float* rs = &xs[0][0];             // reuse xs LDS (done with it)
    float* rq = rs + COUT;
    __syncthreads();
    if (tid < COUT) { rs[tid] = 0.f; rq[tid] = 0.f; }
    __syncthreads();
    #pragma unroll
    for (int j = 0; j < CW; ++j) {
      atomicAdd(&rs[c0 + j], sts[j]);
      atomicAdd(&rq[c0 + j], stq[j]);
    }
    __syncthreads();
    if (tid < COUT) {
      atomicAdd(gso + tid, rs[tid]);
      atomicAdd(gqo + tid, rq[tid]);
    }
  }
}

// ---------------- kNN-16: one wave per query, ballot-select + cross-lane sorted list ----------------
// Top-16 list lives across lanes (lane l holds list[l&15], replicated x4). 128 candidates per
// iteration (2 per lane). ballot(d2 < tau) selects; selected candidates are serialized in
// increasing-j order and inserted via a parallel shfl_up shift. No per-insert tau recheck:
// inserting a candidate >= list[15] is a natural no-op (no lane passes lval > v), so tau is
// refreshed only once per half-chunk — removes the readlane->cmp->branch serial chain.
// Strict < everywhere keeps first-scanned on ties, matching jax.lax.top_k (smaller index first).
// d2 rounding matches reference: (sq_i + sq_j) - 2*dot with _rn ops, no FMA contraction.
__global__ __launch_bounds__(256) void k_knn(const float4* __restrict__ pts4, int* __restrict__ idxout)
{
  int lane = threadIdx.x & 63;
  int wv = (blockIdx.x * 256 + threadIdx.x) >> 6;   // global wave id = query id
  int b = wv >> 13, q = wv & (NN - 1);
  const float4* pb = pts4 + (size_t)b * NN;
  float4 qp = pb[q];
  float lval = 3.4e38f;   // list value held by this lane (ascending in l16)
  int   lidx = 0;
  float tau  = 3.4e38f;   // wave-uniform 16th-best
  int l16 = lane & 15;
  for (int c = 0; c < 64; ++c) {
    int j0 = c * 128 + lane;
    int j1 = j0 + 64;
    float4 cn0 = pb[j0];
    float4 cn1 = pb[j1];
    float dot0 = __fadd_rn(__fadd_rn(__fmul_rn(qp.x,cn0.x), __fmul_rn(qp.y,cn0.y)), __fmul_rn(qp.z,cn0.z));
    float d20  = __fsub_rn(__fadd_rn(qp.w, cn0.w), __fmul_rn(2.0f, dot0));
    float dot1 = __fadd_rn(__fadd_rn(__fmul_rn(qp.x,cn1.x), __fmul_rn(qp.y,cn1.y)), __fmul_rn(qp.z,cn1.z));
    float d21  = __fsub_rn(__fadd_rn(qp.w, cn1.w), __fmul_rn(2.0f, dot1));
    if (j0 == q) d20 = 3.4e38f;
    if (j1 == q) d21 = 3.4e38f;
    unsigned long long m0 = __ballot(d20 < tau);
    if (m0) {
      do {
        int src = __ffsll(m0) - 1;                   // lowest lane first -> increasing j
        m0 &= m0 - 1;
        float v = __uint_as_float(__builtin_amdgcn_readlane(__float_as_uint(d20), src));
        int jc = c * 128 + src;
        float pv = __shfl_up(lval, 1, 16);
        int   pi = __shfl_up(lidx, 1, 16);
        bool atpos = (l16 == 0) || (pv <= v);
        if (lval > v) {
          lval = atpos ? v  : pv;
          lidx = atpos ? jc : pi;
        }
      } while (m0);
      tau = __uint_as_float(__builtin_amdgcn_readlane(__float_as_uint(lval), 15));
    }
    unsigned long long m1 = __ballot(d21 < tau);
    if (m1) {
      do {
        int src = __ffsll(m1) - 1;
        m1 &= m1 - 1;
        float v = __uint_as_float(__builtin_amdgcn_readlane(__float_as_uint(d21), src));
        int jc = c * 128 + 64 + src;
        float pv = __shfl_up(lval, 1, 16);
        int   pi = __shfl_up(lidx, 1, 16);
        bool atpos = (l16 == 0) || (pv <= v);
        if (lval > v) {
          lval = atpos ? v  : pv;
          lidx = atpos ? jc : pi;
        }
      } while (m1);
      tau = __uint_as_float(__builtin_amdgcn_readlane(__float_as_uint(lval), 15));
    }
  }
  if (lane < 16) idxout[(size_t)wv * KNN + lane] = lidx;
}

// ---------------- PointTransformerConv: one wave per point (32768 waves), fused output stats.
// idx row loaded lane-parallel once; per-neighbor j via readlane -> scalar base addressing. ----------------
__global__ __launch_bounds__(256) void k_conv(const float* __restrict__ V, const float* __restrict__ S,
    const float* __restrict__ D, const float* __restrict__ pts, const int* __restrict__ idx,
    const float* __restrict__ pw, const float* __restrict__ pbv, float* __restrict__ Y,
    float* __restrict__ gso, float* __restrict__ gqo)
{
  int lane = threadIdx.x & 63;
  int p = (blockIdx.x * 256 + threadIdx.x) >> 6;   // one wave per point
  int b = p >> 13, self = p & (NN - 1);
  int c0 = lane * 2;
  float2 w0  = *(const float2*)(pw + c0);
  float2 w1  = *(const float2*)(pw + 128 + c0);
  float2 w2  = *(const float2*)(pw + 256 + c0);
  float2 pb2 = *(const float2*)(pbv + c0);
  const float* pbase = pts + (size_t)b * NN * 3;
  float pix = pbase[self*3+0], piy = pbase[self*3+1], piz = pbase[self*3+2];
  int jv = (lane < 16) ? idx[(size_t)p*KNN + lane] : 0;
  float2 di = *(const float2*)(D + (size_t)p*128 + c0);
  float m0 = -3.4e38f, m1 = -3.4e38f, l0 = 0.f, l1 = 0.f, a0 = 0.f, a1 = 0.f;
  #pragma unroll
  for (int t = 0; t < 17; ++t) {         // 16 kNN + self loop (appended last, as in reference)
    int j = (t < 16) ? __builtin_amdgcn_readlane(jv, t) : self;
    float dx = pix - pbase[j*3+0];
    float dy = piy - pbase[j*3+1];
    float dz = piz - pbase[j*3+2];
    size_t off = ((size_t)b * NN + j) * 128 + c0;
    float2 sj = *(const float2*)(S + off);
    float2 vj = *(const float2*)(V + off);
    float de0 = fmaf(dz, w2.x, fmaf(dy, w1.x, fmaf(dx, w0.x, pb2.x)));
    float de1 = fmaf(dz, w2.y, fmaf(dy, w1.y, fmaf(dx, w0.y, pb2.y)));
    float g0 = di.x - sj.x + de0;
    float g1 = di.y - sj.y + de1;
    float mn0 = fmaxf(m0, g0), mn1 = fmaxf(m1, g1);
    float cr0 = __expf(m0 - mn0), cr1 = __expf(m1 - mn1);
    float e0  = __expf(g0 - mn0), e1  = __expf(g1 - mn1);
    l0 = fmaf(l0, cr0, e0);
    l1 = fmaf(l1, cr1, e1);
    a0 = fmaf(a0, cr0, e0 * (vj.x + de0));
    a1 = fmaf(a1, cr1, e1 * (vj.y + de1));
    m0 = mn0; m1 = mn1;
  }
  float2 o; o.x = a0 / l0; o.y = a1 / l1;
  *(float2*)(Y + (size_t)p*128 + c0) = o;
  // fused per-channel stats over the block's 4 points
  __shared__ float rs[128], rq[128];
  int tid = threadIdx.x;
  if (tid < 128) { rs[tid] = 0.f; rq[tid] = 0.f; }
  __syncthreads();
  atomicAdd(&rs[c0],     o.x);
  atomicAdd(&rs[c0 + 1], o.y);
  atomicAdd(&rq[c0],     o.x * o.x);
  atomicAdd(&rq[c0 + 1], o.y * o.y);
  __syncthreads();
  if (tid < 128) {
    atomicAdd(gso + tid, rs[tid]);
    atomicAdd(gqo + tid, rq[tid]);
  }
}

// ---------------- decoder head: logits = relu(bn(t)) @ dec_w2 + dec_b2, BN finalize inline ----------------
__global__ __launch_bounds__(256) void k_dec2(const float* __restrict__ T,
    const float* __restrict__ gsi, const float* __restrict__ gqi,
    const float* __restrict__ bng, const float* __restrict__ bnb,
    const float* __restrict__ W, const float* __restrict__ bias, float* __restrict__ out)
{
  __shared__ float xs[64][132];   // row stride 132 floats -> 16B-aligned float4 rows
  __shared__ float wt[13][128];
  __shared__ float scf[128], shf[128];
  int tid = threadIdx.x;
  int pb = blockIdx.x * 64;
  if (tid < 128) {
    float mean = gsi[tid] * (1.0f / PP);
    float var  = gqi[tid] * (1.0f / PP) - mean * mean;
    float sres = bng[tid] / sqrtf(var + 1e-5f);
    scf[tid] = sres;
    shf[tid] = bnb[tid] - mean * sres;
  }
  for (int i = tid; i < 13 * 128; i += 256) {
    int cls = i >> 7, k = i & 127;
    wt[cls][k] = W[k*13 + cls];
  }
  __syncthreads();
  for (int i = tid; i < 64 * 32; i += 256) {
    int p = i >> 5, k = (i & 31) * 4;
    float4 v = *(const float4*)(T + (size_t)(pb + p)*128 + k);
    v.x = fmaxf(fmaf(v.x, scf[k+0], shf[k+0]), 0.f);
    v.y = fmaxf(fmaf(v.y, scf[k+1], shf[k+1]), 0.f);
    v.z = fmaxf(fmaf(v.z, scf[k+2], shf[k+2]), 0.f);
    v.w = fmaxf(fmaf(v.w, scf[k+3], shf[k+3]), 0.f);
    xs[p][k+0] = v.x; xs[p][k+1] = v.y; xs[p][k+2] = v.z; xs[p][k+3] = v.w;
  }
  __syncthreads();
  for (int o = tid; o < 64 * 13; o += 256) {
    int p = o / 13, cls = o - p * 13;
    float acc = bias[cls];
    const float4* xr = (const float4*)&xs[p][0];
    const float4* wr = (const float4*)&wt[cls][0];
    #pragma unroll 8
    for (int k4 = 0; k4 < 32; ++k4) {
      float4 a = xr[k4], w = wr[k4];
      acc = fmaf(a.x, w.x, acc);
      acc = fmaf(a.y, w.y, acc);
      acc = fmaf(a.z, w.z, acc);
      acc = fmaf(a.w, w.w, acc);
    }
    out[(size_t)(pb + p)*13 + cls] = acc;
  }
}

extern "C" void kernel_launch(void* const* d_in, const int* in_sizes, int n_in,
                              void* d_out, int out_size, void* d_ws, size_t ws_size,
                              hipStream_t stream)
{
  const float* pts      = (const float*)d_in[0];
  const float* embed_w1 = (const float*)d_in[1];
  const float* embed_b1 = (const float*)d_in[2];
  const float* bn1_g    = (const float*)d_in[3];
  const float* bn1_b    = (const float*)d_in[4];
  const float* embed_w2 = (const float*)d_in[5];
  const float* embed_b2 = (const float*)d_in[6];
  const float* bne_g    = (const float*)d_in[7];
  const float* bne_b    = (const float*)d_in[8];
  const float* l0_lin   = (const float*)d_in[9];
  const float* l0_src   = (const float*)d_in[10];
  const float* l0_dst   = (const float*)d_in[11];
  const float* l0_pos_w = (const float*)d_in[12];
  const float* l0_pos_b = (const float*)d_in[13];
  const float* l0_bn_g  = (const float*)d_in[14];
  const float* l0_bn_b  = (const float*)d_in[15];
  const float* l1_lin   = (const float*)d_in[16];
  const float* l1_src   = (const float*)d_in[17];
  const float* l1_dst   = (const float*)d_in[18];
  const float* l1_pos_w = (const float*)d_in[19];
  const float* l1_pos_b = (const float*)d_in[20];
  const float* l1_bn_g  = (const float*)d_in[21];
  const float* l1_bn_b  = (const float*)d_in[22];
  const float* dec_w1   = (const float*)d_in[23];
  const float* dec_b1   = (const float*)d_in[24];
  const float* dec_bn_g = (const float*)d_in[25];
  const float* dec_bn_b = (const float*)d_in[26];
  const float* dec_w2   = (const float*)d_in[27];
  const float* dec_b2   = (const float*)d_in[28];

  char* ws = (char*)d_ws;
  const size_t MB = 1024 * 1024;
  float* h1  = (float*)(ws + 0);          // 8 MB  [P,64]
  float* h2  = (float*)(ws + 8*MB);       // 8 MB  [P,64]
  int*   idx = (int*)  (ws + 16*MB);      // 2 MB  [P,16]
  float* v0  = (float*)(ws + 18*MB);      // 16 MB [P,128]  (reused for layer1)
  float* s0  = (float*)(ws + 34*MB);      // 16 MB
  float* d0  = (float*)(ws + 50*MB);      // 16 MB
  float* y0  = (float*)(ws + 66*MB);      // 16 MB
  float* y1  = (float*)(ws + 82*MB);      // 16 MB
  float* tt  = (float*)(ws + 0);          // 16 MB overlay on h1/h2 (dead by then)
  float4* pts4 = (float4*)(ws + 18*MB);   // 512 KB overlay on v0 (dead once layer-0 proj runs)
  float* st  = (float*)(ws + 98*MB);      // stats: 5 x (sum, sumsq)
  float *sum1=st+0,    *ss1=st+128;
  float *sum2=st+256,  *ss2=st+384;
  float *sum3=st+512,  *ss3=st+640;
  float *sum4=st+768,  *ss4=st+896;
  float *sum5=st+1024, *ss5=st+1152;

  hipMemsetAsync(st, 0, 1536 * sizeof(float), stream);

  // kNN graph (pts4 overlays v0, which is only written after k_knn completes)
  k_prep<<<128, 256, 0, stream>>>(pts, pts4);
  k_knn<<<8192, 256, 0, stream>>>(pts4, idx);

  // embedding MLP (stats fused into producers; BN finalize inline in consumers)
  k_embed1<<<128, 256, 0, stream>>>(pts, embed_w1, embed_b1, h1, sum1, ss1);
  k_proj<64,64><<<dim3(512,1), 256, 0, stream>>>(h1, sum1, ss1, bn1_g, bn1_b,
      embed_w2, embed_w2, embed_w2, embed_b2, embed_b2, embed_b2, h2, h2, h2, sum2, ss2);

  // layer 0
  k_proj<64,128><<<dim3(512,3), 256, 0, stream>>>(h2, sum2, ss2, bne_g, bne_b,
      l0_lin, l0_src, l0_dst, nullptr, nullptr, nullptr, v0, s0, d0, nullptr, nullptr);
  k_conv<<<8192, 256, 0, stream>>>(v0, s0, d0, pts, idx, l0_pos_w, l0_pos_b, y0, sum3, ss3);

  // layer 1
  k_proj<128,128><<<dim3(512,3), 256, 0, stream>>>(y0, sum3, ss3, l0_bn_g, l0_bn_b,
      l1_lin, l1_src, l1_dst, nullptr, nullptr, nullptr, v0, s0, d0, nullptr, nullptr);
  k_conv<<<8192, 256, 0, stream>>>(v0, s0, d0, pts, idx, l1_pos_w, l1_pos_b, y1, sum4, ss4);

  // decoder
  k_proj<128,128><<<dim3(512,1), 256, 0, stream>>>(y1, sum4, ss4, l1_bn_g, l1_bn_b,
      dec_w1, dec_w1, dec_w1, dec_b1, dec_b1, dec_b1, tt, tt, tt, sum5, ss5);
  k_dec2<<<512, 256, 0, stream>>>(tt, sum5, ss5, dec_bn_g, dec_bn_b, dec_w2, dec_b2, (float*)d_out);
}

// Round 4
// 896.234 us; speedup vs baseline: 1.0232x; 1.0232x over previous
//
#include <hip/hip_runtime.h>
#include <math.h>

#define BB 4
#define NN 8192
#define PP 32768
#define KNN 16

// ---------------- embed1: h1 = pts @ w1 + b1  [P,64], fused BN stats ----------------
__global__ __launch_bounds__(256) void k_embed1(const float* __restrict__ pts,
    const float* __restrict__ w1, const float* __restrict__ b1, float* __restrict__ h1,
    float* __restrict__ gsum, float* __restrict__ gss)
{
  int tid = threadIdx.x;
  int c = tid & 63, g = tid >> 6;
  float wx = w1[c], wy = w1[64 + c], wz = w1[128 + c], bc = b1[c];
  int base = blockIdx.x * 256;
  float s = 0.f, ss = 0.f;
  #pragma unroll 4
  for (int i = 0; i < 64; ++i) {
    int p = base + g + i * 4;
    float px = pts[p*3+0], py = pts[p*3+1], pz = pts[p*3+2];
    float h = fmaf(pz, wz, fmaf(py, wy, fmaf(px, wx, bc)));
    h1[(size_t)p*64 + c] = h;
    s += h; ss = fmaf(h, h, ss);
  }
  __shared__ float ls[256], lq[256];
  ls[tid] = s; lq[tid] = ss;
  __syncthreads();
  if (tid < 64) {
    float a = ls[tid] + ls[tid+64] + ls[tid+128] + ls[tid+192];
    float b2 = lq[tid] + lq[tid+64] + lq[tid+128] + lq[tid+192];
    atomicAdd(gsum + tid, a);
    atomicAdd(gss + tid, b2);
  }
}

// ---------------- prep for kNN/conv: pts4[p] = (x,y,z,|p|^2) ----------------
__global__ __launch_bounds__(256) void k_prep(const float* __restrict__ pts, float4* __restrict__ pts4)
{
  int p = blockIdx.x * 256 + threadIdx.x;
  float x = pts[p*3+0], y = pts[p*3+1], z = pts[p*3+2];
  float sq = __fadd_rn(__fadd_rn(__fmul_rn(x,x), __fmul_rn(y,y)), __fmul_rn(z,z));
  pts4[p] = make_float4(x, y, z, sq);
}

// ---------------- generic projection: out = relu(bn(in)) @ W (+bias), BN finalize inline,
// optional fused output stats. blockIdx.y selects one of up to 3 (W,bias,out) triples. ----------------
template<int K, int COUT>
__global__ __launch_bounds__(256) void k_proj(const float* __restrict__ in,
    const float* __restrict__ gsi, const float* __restrict__ gqi,
    const float* __restrict__ bng, const float* __restrict__ bnb,
    const float* __restrict__ W0, const float* __restrict__ W1, const float* __restrict__ W2,
    const float* __restrict__ B0, const float* __restrict__ B1, const float* __restrict__ B2,
    float* __restrict__ O0, float* __restrict__ O1, float* __restrict__ O2,
    float* __restrict__ gso, float* __restrict__ gqo)
{
  constexpr int PTS = 64;
  constexpr int CW = 8;
  constexpr int CG = COUT / CW;        // channel groups: 8 (COUT=64) or 16 (COUT=128)
  constexpr int PW = PTS * CG / 256;   // points per thread: 2 or 4
  const float* W  = (blockIdx.y == 0) ? W0 : (blockIdx.y == 1) ? W1 : W2;
  const float* Bb = (blockIdx.y == 0) ? B0 : (blockIdx.y == 1) ? B1 : B2;
  float*       O  = (blockIdx.y == 0) ? O0 : (blockIdx.y == 1) ? O1 : O2;
  __shared__ float xs[PTS][K + 1];
  __shared__ float scf[K], shf[K];
  int tid = threadIdx.x;
  int pbase = blockIdx.x * PTS;
  if (tid < K) {                       // inline BN finalize from raw sums
    float mean = gsi[tid] * (1.0f / PP);
    float var  = gqi[tid] * (1.0f / PP) - mean * mean;
    float sres = bng[tid] / sqrtf(var + 1e-5f);
    scf[tid] = sres;
    shf[tid] = bnb[tid] - mean * sres;
  }
  __syncthreads();
  constexpr int T4 = PTS * K / 4;
  for (int i = tid; i < T4; i += 256) {
    int p = i / (K/4), k = (i % (K/4)) * 4;
    float4 v = *(const float4*)(in + (size_t)(pbase + p)*K + k);
    v.x = fmaxf(fmaf(v.x, scf[k+0], shf[k+0]), 0.f);
    v.y = fmaxf(fmaf(v.y, scf[k+1], shf[k+1]), 0.f);
    v.z = fmaxf(fmaf(v.z, scf[k+2], shf[k+2]), 0.f);
    v.w = fmaxf(fmaf(v.w, scf[k+3], shf[k+3]), 0.f);
    xs[p][k+0] = v.x; xs[p][k+1] = v.y; xs[p][k+2] = v.z; xs[p][k+3] = v.w;
  }
  __syncthreads();
  int cg = tid % CG, pg = tid / CG;
  int c0 = cg * CW, p0 = pg * PW;
  float acc[PW][CW];
  #pragma unroll
  for (int i = 0; i < PW; ++i) {
    #pragma unroll
    for (int j = 0; j < CW; ++j) acc[i][j] = 0.f;
  }
  #pragma unroll 4
  for (int k = 0; k < K; ++k) {
    float4 wa = *(const float4*)(W + (size_t)k*COUT + c0);
    float4 wb = *(const float4*)(W + (size_t)k*COUT + c0 + 4);
    #pragma unroll
    for (int i = 0; i < PW; ++i) {
      float x = xs[p0 + i][k];
      acc[i][0] = fmaf(x, wa.x, acc[i][0]);
      acc[i][1] = fmaf(x, wa.y, acc[i][1]);
      acc[i][2] = fmaf(x, wa.z, acc[i][2]);
      acc[i][3] = fmaf(x, wa.w, acc[i][3]);
      acc[i][4] = fmaf(x, wb.x, acc[i][4]);
      acc[i][5] = fmaf(x, wb.y, acc[i][5]);
      acc[i][6] = fmaf(x, wb.z, acc[i][6]);
      acc[i][7] = fmaf(x, wb.w, acc[i][7]);
    }
  }
  float bj[CW];
  #pragma unroll
  for (int j = 0; j < CW; ++j) bj[j] = Bb ? Bb[c0 + j] : 0.f;
  float sts[CW], stq[CW];
  #pragma unroll
  for (int j = 0; j < CW; ++j) { sts[j] = 0.f; stq[j] = 0.f; }
  #pragma unroll
  for (int i = 0; i < PW; ++i) {
    float o[CW];
    #pragma unroll
    for (int j = 0; j < CW; ++j) {
      o[j] = acc[i][j] + bj[j];
      sts[j] += o[j];
      stq[j] = fmaf(o[j], o[j], stq[j]);
    }
    float* op = O + (size_t)(pbase + p0 + i)*COUT + c0;
    *(float4*)(op)     = make_float4(o[0], o[1], o[2], o[3]);
    *(float4*)(op + 4) = make_float4(o[4], o[5], o[6], o[7]);
  }
  if (gso) {                           // fused output stats (single-output dispatches only)
    float* rs = &xs[0][0];             // reuse xs LDS (done with it)
    float* rq = rs + COUT;
    __syncthreads();
    if (tid < COUT) { rs[tid] = 0.f; rq[tid] = 0.f; }
    __syncthreads();
    #pragma unroll
    for (int j = 0; j < CW; ++j) {
      atomicAdd(&rs[c0 + j], sts[j]);
      atomicAdd(&rq[c0 + j], stq[j]);
    }
    __syncthreads();
    if (tid < COUT) {
      atomicAdd(gso + tid, rs[tid]);
      atomicAdd(gqo + tid, rq[tid]);
    }
  }
}

// ---------------- kNN-16: one wave per query, ballot-select + cross-lane sorted list ----------------
__global__ __launch_bounds__(256) void k_knn(const float4* __restrict__ pts4, int* __restrict__ idxout)
{
  int lane = threadIdx.x & 63;
  int wv = (blockIdx.x * 256 + threadIdx.x) >> 6;   // global wave id = query id
  int b = wv >> 13, q = wv & (NN - 1);
  const float4* pb = pts4 + (size_t)b * NN;
  float4 qp = pb[q];
  float lval = 3.4e38f;   // list value held by this lane (ascending in l16)
  int   lidx = 0;
  float tau  = 3.4e38f;   // wave-uniform 16th-best
  int l16 = lane & 15;
  for (int c = 0; c < 64; ++c) {
    int j0 = c * 128 + lane;
    int j1 = j0 + 64;
    float4 cn0 = pb[j0];
    float4 cn1 = pb[j1];
    float dot0 = __fadd_rn(__fadd_rn(__fmul_rn(qp.x,cn0.x), __fmul_rn(qp.y,cn0.y)), __fmul_rn(qp.z,cn0.z));
    float d20  = __fsub_rn(__fadd_rn(qp.w, cn0.w), __fmul_rn(2.0f, dot0));
    float dot1 = __fadd_rn(__fadd_rn(__fmul_rn(qp.x,cn1.x), __fmul_rn(qp.y,cn1.y)), __fmul_rn(qp.z,cn1.z));
    float d21  = __fsub_rn(__fadd_rn(qp.w, cn1.w), __fmul_rn(2.0f, dot1));
    if (j0 == q) d20 = 3.4e38f;
    if (j1 == q) d21 = 3.4e38f;
    unsigned long long m0 = __ballot(d20 < tau);
    if (m0) {
      do {
        int src = __ffsll(m0) - 1;                   // lowest lane first -> increasing j
        m0 &= m0 - 1;
        float v = __uint_as_float(__builtin_amdgcn_readlane(__float_as_uint(d20), src));
        int jc = c * 128 + src;
        float pv = __shfl_up(lval, 1, 16);
        int   pi = __shfl_up(lidx, 1, 16);
        bool atpos = (l16 == 0) || (pv <= v);
        if (lval > v) {
          lval = atpos ? v  : pv;
          lidx = atpos ? jc : pi;
        }
      } while (m0);
      tau = __uint_as_float(__builtin_amdgcn_readlane(__float_as_uint(lval), 15));
    }
    unsigned long long m1 = __ballot(d21 < tau);
    if (m1) {
      do {
        int src = __ffsll(m1) - 1;
        m1 &= m1 - 1;
        float v = __uint_as_float(__builtin_amdgcn_readlane(__float_as_uint(d21), src));
        int jc = c * 128 + 64 + src;
        float pv = __shfl_up(lval, 1, 16);
        int   pi = __shfl_up(lidx, 1, 16);
        bool atpos = (l16 == 0) || (pv <= v);
        if (lval > v) {
          lval = atpos ? v  : pv;
          lidx = atpos ? jc : pi;
        }
      } while (m1);
      tau = __uint_as_float(__builtin_amdgcn_readlane(__float_as_uint(lval), 15));
    }
  }
  if (lane < 16) idxout[(size_t)wv * KNN + lane] = lidx;
}

// ---------------- PointTransformerConv: one wave per point, DEEP-PREFETCH gather.
// Phase A issues all 34 neighbor-row loads (sj/vj, 512 B per wave each) before any use ->
// ~34 outstanding vmem ops per wave instead of ~2 (R3 was latency-bound: VALUBusy 16.7%,
// 990 GB/s). Neighbor positions are wave-uniform (SGPR index from readlane) -> s_load from
// pts4, L1-hot (96 KB/batch). Fused per-channel output stats as before. ----------------
__global__ __launch_bounds__(256) void k_conv(const float* __restrict__ V, const float* __restrict__ S,
    const float* __restrict__ D, const float4* __restrict__ pts4, const int* __restrict__ idx,
    const float* __restrict__ pw, const float* __restrict__ pbv, float* __restrict__ Y,
    float* __restrict__ gso, float* __restrict__ gqo)
{
  int lane = threadIdx.x & 63;
  int p = (blockIdx.x * 256 + threadIdx.x) >> 6;   // one wave per point
  int b = p >> 13, self = p & (NN - 1);
  int c0 = lane * 2;
  float2 w0  = *(const float2*)(pw + c0);
  float2 w1  = *(const float2*)(pw + 128 + c0);
  float2 w2  = *(const float2*)(pw + 256 + c0);
  float2 pb2 = *(const float2*)(pbv + c0);
  const float4* pb4 = pts4 + (size_t)b * NN;
  int jv = (lane < 16) ? idx[(size_t)p*KNN + lane] : 0;
  float2 di = *(const float2*)(D + (size_t)p*128 + c0);
  float4 pi = pb4[self];
  int js[17];
  #pragma unroll
  for (int t = 0; t < 16; ++t) js[t] = __builtin_amdgcn_readlane(jv, t);
  js[16] = self;                        // self loop appended last, as in reference
  const float* Sb = S + (size_t)b * NN * 128 + c0;
  const float* Vb = V + (size_t)b * NN * 128 + c0;
  float2 sj[17], vj[17];
  #pragma unroll
  for (int t = 0; t < 17; ++t) {        // phase A: all gathers in flight
    sj[t] = *(const float2*)(Sb + (size_t)js[t] * 128);
    vj[t] = *(const float2*)(Vb + (size_t)js[t] * 128);
  }
  float m0 = -3.4e38f, m1 = -3.4e38f, l0 = 0.f, l1 = 0.f, a0 = 0.f, a1 = 0.f;
  #pragma unroll
  for (int t = 0; t < 17; ++t) {        // phase B: online softmax
    float4 pj = pb4[js[t]];             // uniform address -> s_load, L1-hot
    float dx = pi.x - pj.x, dy = pi.y - pj.y, dz = pi.z - pj.z;
    float de0 = fmaf(dz, w2.x, fmaf(dy, w1.x, fmaf(dx, w0.x, pb2.x)));
    float de1 = fmaf(dz, w2.y, fmaf(dy, w1.y, fmaf(dx, w0.y, pb2.y)));
    float g0 = di.x - sj[t].x + de0;
    float g1 = di.y - sj[t].y + de1;
    float mn0 = fmaxf(m0, g0), mn1 = fmaxf(m1, g1);
    float cr0 = __expf(m0 - mn0), cr1 = __expf(m1 - mn1);
    float e0  = __expf(g0 - mn0), e1  = __expf(g1 - mn1);
    l0 = fmaf(l0, cr0, e0);
    l1 = fmaf(l1, cr1, e1);
    a0 = fmaf(a0, cr0, e0 * (vj[t].x + de0));
    a1 = fmaf(a1, cr1, e1 * (vj[t].y + de1));
    m0 = mn0; m1 = mn1;
  }
  float2 o; o.x = a0 / l0; o.y = a1 / l1;
  *(float2*)(Y + (size_t)p*128 + c0) = o;
  // fused per-channel stats over the block's 4 points
  __shared__ float rs[128], rq[128];
  int tid = threadIdx.x;
  if (tid < 128) { rs[tid] = 0.f; rq[tid] = 0.f; }
  __syncthreads();
  atomicAdd(&rs[c0],     o.x);
  atomicAdd(&rs[c0 + 1], o.y);
  atomicAdd(&rq[c0],     o.x * o.x);
  atomicAdd(&rq[c0 + 1], o.y * o.y);
  __syncthreads();
  if (tid < 128) {
    atomicAdd(gso + tid, rs[tid]);
    atomicAdd(gqo + tid, rq[tid]);
  }
}

// ---------------- decoder head: logits = relu(bn(t)) @ dec_w2 + dec_b2, BN finalize inline ----------------
__global__ __launch_bounds__(256) void k_dec2(const float* __restrict__ T,
    const float* __restrict__ gsi, const float* __restrict__ gqi,
    const float* __restrict__ bng, const float* __restrict__ bnb,
    const float* __restrict__ W, const float* __restrict__ bias, float* __restrict__ out)
{
  __shared__ float xs[64][132];   // row stride 132 floats -> 16B-aligned float4 rows
  __shared__ float wt[13][128];
  __shared__ float scf[128], shf[128];
  int tid = threadIdx.x;
  int pb = blockIdx.x * 64;
  if (tid < 128) {
    float mean = gsi[tid] * (1.0f / PP);
    float var  = gqi[tid] * (1.0f / PP) - mean * mean;
    float sres = bng[tid] / sqrtf(var + 1e-5f);
    scf[tid] = sres;
    shf[tid] = bnb[tid] - mean * sres;
  }
  for (int i = tid; i < 13 * 128; i += 256) {
    int cls = i >> 7, k = i & 127;
    wt[cls][k] = W[k*13 + cls];
  }
  __syncthreads();
  for (int i = tid; i < 64 * 32; i += 256) {
    int p = i >> 5, k = (i & 31) * 4;
    float4 v = *(const float4*)(T + (size_t)(pb + p)*128 + k);
    v.x = fmaxf(fmaf(v.x, scf[k+0], shf[k+0]), 0.f);
    v.y = fmaxf(fmaf(v.y, scf[k+1], shf[k+1]), 0.f);
    v.z = fmaxf(fmaf(v.z, scf[k+2], shf[k+2]), 0.f);
    v.w = fmaxf(fmaf(v.w, scf[k+3], shf[k+3]), 0.f);
    xs[p][k+0] = v.x; xs[p][k+1] = v.y; xs[p][k+2] = v.z; xs[p][k+3] = v.w;
  }
  __syncthreads();
  for (int o = tid; o < 64 * 13; o += 256) {
    int p = o / 13, cls = o - p * 13;
    float acc = bias[cls];
    const float4* xr = (const float4*)&xs[p][0];
    const float4* wr = (const float4*)&wt[cls][0];
    #pragma unroll 8
    for (int k4 = 0; k4 < 32; ++k4) {
      float4 a = xr[k4], w = wr[k4];
      acc = fmaf(a.x, w.x, acc);
      acc = fmaf(a.y, w.y, acc);
      acc = fmaf(a.z, w.z, acc);
      acc = fmaf(a.w, w.w, acc);
    }
    out[(size_t)(pb + p)*13 + cls] = acc;
  }
}

extern "C" void kernel_launch(void* const* d_in, const int* in_sizes, int n_in,
                              void* d_out, int out_size, void* d_ws, size_t ws_size,
                              hipStream_t stream)
{
  const float* pts      = (const float*)d_in[0];
  const float* embed_w1 = (const float*)d_in[1];
  const float* embed_b1 = (const float*)d_in[2];
  const float* bn1_g    = (const float*)d_in[3];
  const float* bn1_b    = (const float*)d_in[4];
  const float* embed_w2 = (const float*)d_in[5];
  const float* embed_b2 = (const float*)d_in[6];
  const float* bne_g    = (const float*)d_in[7];
  const float* bne_b    = (const float*)d_in[8];
  const float* l0_lin   = (const float*)d_in[9];
  const float* l0_src   = (const float*)d_in[10];
  const float* l0_dst   = (const float*)d_in[11];
  const float* l0_pos_w = (const float*)d_in[12];
  const float* l0_pos_b = (const float*)d_in[13];
  const float* l0_bn_g  = (const float*)d_in[14];
  const float* l0_bn_b  = (const float*)d_in[15];
  const float* l1_lin   = (const float*)d_in[16];
  const float* l1_src   = (const float*)d_in[17];
  const float* l1_dst   = (const float*)d_in[18];
  const float* l1_pos_w = (const float*)d_in[19];
  const float* l1_pos_b = (const float*)d_in[20];
  const float* l1_bn_g  = (const float*)d_in[21];
  const float* l1_bn_b  = (const float*)d_in[22];
  const float* dec_w1   = (const float*)d_in[23];
  const float* dec_b1   = (const float*)d_in[24];
  const float* dec_bn_g = (const float*)d_in[25];
  const float* dec_bn_b = (const float*)d_in[26];
  const float* dec_w2   = (const float*)d_in[27];
  const float* dec_b2   = (const float*)d_in[28];

  char* ws = (char*)d_ws;
  const size_t MB = 1024 * 1024;
  float* h1  = (float*)(ws + 0);          // 8 MB  [P,64]
  float* h2  = (float*)(ws + 8*MB);       // 8 MB  [P,64]
  int*   idx = (int*)  (ws + 16*MB);      // 2 MB  [P,16]
  float* v0  = (float*)(ws + 18*MB);      // 16 MB [P,128]  (reused for layer1)
  float* s0  = (float*)(ws + 34*MB);      // 16 MB
  float* d0  = (float*)(ws + 50*MB);      // 16 MB
  float* y0  = (float*)(ws + 66*MB);      // 16 MB
  float* y1  = (float*)(ws + 82*MB);      // 16 MB
  float* tt  = (float*)(ws + 0);          // 16 MB overlay on h1/h2 (dead by then)
  float* st  = (float*)(ws + 98*MB);      // stats: 5 x (sum, sumsq)
  float4* pts4 = (float4*)(ws + 98*MB + 65536);  // 512 KB, lives until last k_conv
  float *sum1=st+0,    *ss1=st+128;
  float *sum2=st+256,  *ss2=st+384;
  float *sum3=st+512,  *ss3=st+640;
  float *sum4=st+768,  *ss4=st+896;
  float *sum5=st+1024, *ss5=st+1152;

  hipMemsetAsync(st, 0, 1536 * sizeof(float), stream);

  // kNN graph
  k_prep<<<128, 256, 0, stream>>>(pts, pts4);
  k_knn<<<8192, 256, 0, stream>>>(pts4, idx);

  // embedding MLP (stats fused into producers; BN finalize inline in consumers)
  k_embed1<<<128, 256, 0, stream>>>(pts, embed_w1, embed_b1, h1, sum1, ss1);
  k_proj<64,64><<<dim3(512,1), 256, 0, stream>>>(h1, sum1, ss1, bn1_g, bn1_b,
      embed_w2, embed_w2, embed_w2, embed_b2, embed_b2, embed_b2, h2, h2, h2, sum2, ss2);

  // layer 0
  k_proj<64,128><<<dim3(512,3), 256, 0, stream>>>(h2, sum2, ss2, bne_g, bne_b,
      l0_lin, l0_src, l0_dst, nullptr, nullptr, nullptr, v0, s0, d0, nullptr, nullptr);
  k_conv<<<8192, 256, 0, stream>>>(v0, s0, d0, pts4, idx, l0_pos_w, l0_pos_b, y0, sum3, ss3);

  // layer 1
  k_proj<128,128><<<dim3(512,3), 256, 0, stream>>>(y0, sum3, ss3, l0_bn_g, l0_bn_b,
      l1_lin, l1_src, l1_dst, nullptr, nullptr, nullptr, v0, s0, d0, nullptr, nullptr);
  k_conv<<<8192, 256, 0, stream>>>(v0, s0, d0, pts4, idx, l1_pos_w, l1_pos_b, y1, sum4, ss4);

  // decoder
  k_proj<128,128><<<dim3(512,1), 256, 0, stream>>>(y1, sum4, ss4, l1_bn_g, l1_bn_b,
      dec_w1, dec_w1, dec_w1, dec_b1, dec_b1, dec_b1, tt, tt, tt, sum5, ss5);
  k_dec2<<<512, 256, 0, stream>>>(tt, sum5, ss5, dec_bn_g, dec_bn_b, dec_w2, dec_b2, (float*)d_out);
}